// Round 1
// baseline (299.803 us; speedup 1.0000x reference)
//
#include <hip/hip_runtime.h>

// x (B=64, C=256, T=2048) fp32; conv_weight (256,256,3); beta (1,); b (256,).
// Output spikes (B,C,T) fp32 in {0,1}.
//
// Established: R5 proved 128-step speculative warmup is bit-exact (absmax 0)
// and buys 8x occupancy. R2 proved the LDS-coalesced shell gives exactly 1.00x
// write amplification. R6 (252.5 us bench / 92.6 us dispatch) combined them but
// left the fill BLOCKING: per-CU accounting showed ~174 cyc per coalesced 1KB
// vmem instr (pure exposed latency; VALUBusy 12.7%, HBM 39% of achievable).
// R7: software-pipeline the fill one phase ahead in REGISTERS (64 VGPRs of
// float4), so the global-load round trip hides under the 64-step compute of
// the previous phase. LDS stays single-buffered (DS ops are in-order per wave:
// next-phase ds_writes cannot bypass this phase's drain ds_reads), so
// occupancy stays 8 waves/CU.
#define C_DIM 256
#define T_DIM 2048
#define B_DIM 64
#define NROWS (B_DIM * C_DIM)          // 16384
#define SEGS 8
#define SEGL (T_DIM / SEGS)            // 256 emitted timesteps per segment
#define WARM 128                       // speculative warmup steps (bit-exact, r5)
#define PW   64                        // phase window: floats per stream per phase
#define NPH  ((WARM + SEGL) / PW)      // 6 phases
#define WARM_PH (WARM / PW)            // 2 warmup phases
#define SPITCH 68                      // LDS floats per stream: 64 + 4 pad ->
                                       // bank-quad (17s+g)%8 = (s+g)%8: even 8-lane spread
#define NSTR 64                        // streams per block (= wave size)

__device__ __forceinline__ float sqrn(float v) { return __fmul_rn(v, v); }

// norm[c] = sum of squares of 768 floats in numpy's exact pairwise order
// (768->384->192->96; 96-blocks via 8-accumulator unrolled loop).
// Verified bit-exact (rounds 1-6 absmax 0). DO NOT change the summation tree.
__global__ __launch_bounds__(64) void norm_kernel(const float* __restrict__ w,
                                                  const float* __restrict__ b,
                                                  float* __restrict__ bn,
                                                  float* __restrict__ ninv) {
    const int c = blockIdx.x;
    const int k = threadIdx.x;
    __shared__ float q[8];
    if (k < 8) {
        const float* a = w + c * 768 + k * 96;
        float r0 = sqrn(a[0]), r1 = sqrn(a[1]), r2 = sqrn(a[2]), r3 = sqrn(a[3]);
        float r4 = sqrn(a[4]), r5 = sqrn(a[5]), r6 = sqrn(a[6]), r7 = sqrn(a[7]);
        #pragma unroll
        for (int i = 8; i < 96; i += 8) {
            r0 = __fadd_rn(r0, sqrn(a[i + 0]));
            r1 = __fadd_rn(r1, sqrn(a[i + 1]));
            r2 = __fadd_rn(r2, sqrn(a[i + 2]));
            r3 = __fadd_rn(r3, sqrn(a[i + 3]));
            r4 = __fadd_rn(r4, sqrn(a[i + 4]));
            r5 = __fadd_rn(r5, sqrn(a[i + 5]));
            r6 = __fadd_rn(r6, sqrn(a[i + 6]));
            r7 = __fadd_rn(r7, sqrn(a[i + 7]));
        }
        q[k] = __fadd_rn(__fadd_rn(__fadd_rn(r0, r1), __fadd_rn(r2, r3)),
                         __fadd_rn(__fadd_rn(r4, r5), __fadd_rn(r6, r7)));
    }
    __syncthreads();
    if (k == 0) {
        float s = __fadd_rn(__fadd_rn(__fadd_rn(q[0], q[1]), __fadd_rn(q[2], q[3])),
                            __fadd_rn(__fadd_rn(q[4], q[5]), __fadd_rn(q[6], q[7])));
        bn[c]   = __fmul_rn(b[c], s);
        ninv[c] = 1.0f / __fadd_rn(s, 1e-8f);
    }
}

// One LIF step, bit-exact vs numpy semantics (verified absmax 0, rounds 4-6):
// speculative dual-path update + sign-bit select, no VCC.
__device__ __forceinline__ float step_fast(float xw, float& mem, int& mask,
                                           float bnc, float beta, float nic, float bc) {
    float m0 = __fmul_rn(mem, beta);
    float m1 = __fmul_rn(__fsub_rn(mem, bnc), beta);
    m0 = __fadd_rn(m0, xw);
    m1 = __fadd_rn(m1, xw);
    int mi = (__float_as_int(m1) & mask) | (__float_as_int(m0) & ~mask);
    mem = __int_as_float(mi);
    float p = __fmul_rn(mem, nic);
    float d = __fsub_rn(bc, p);
    mask = __float_as_int(d) >> 31;                 // -1 if spike else 0
    return __int_as_float(mask & 0x3f800000);       // 1.0f or 0.0f
}

#define STEP4_NOSTORE(v)                                                   \
    do {                                                                   \
        float xw0 = __fmul_rn((v).x, omb);                                 \
        float xw1 = __fmul_rn((v).y, omb);                                 \
        float xw2 = __fmul_rn((v).z, omb);                                 \
        float xw3 = __fmul_rn((v).w, omb);                                 \
        (void)step_fast(xw0, mem, mask, bnc, beta, nic, bc);               \
        (void)step_fast(xw1, mem, mask, bnc, beta, nic, bc);               \
        (void)step_fast(xw2, mem, mask, bnc, beta, nic, bc);               \
        (void)step_fast(xw3, mem, mask, bnc, beta, nic, bc);               \
    } while (0)

#define STEP4_STORE(v, o)                                                  \
    do {                                                                   \
        float xw0 = __fmul_rn((v).x, omb);                                 \
        float xw1 = __fmul_rn((v).y, omb);                                 \
        float xw2 = __fmul_rn((v).z, omb);                                 \
        float xw3 = __fmul_rn((v).w, omb);                                 \
        (o).x = step_fast(xw0, mem, mask, bnc, beta, nic, bc);             \
        (o).y = step_fast(xw1, mem, mask, bnc, beta, nic, bc);             \
        (o).z = step_fast(xw2, mem, mask, bnc, beta, nic, bc);             \
        (o).w = step_fast(xw3, mem, mask, bnc, beta, nic, bc);             \
    } while (0)

// lgkm-only wait: cross-lane LDS handoff within a wave (proven in r2).
#define WAITCNT_LGKM0  0xC07F

// Block = 1 wave = 64 streams (8 rows x 8 segs). 2048 blocks = 8 waves/CU.
// Stream s: row = blockIdx.x*8 + (s>>3), seg = s&7, covers local steps
// [0,384) = global t in [seg*256-128, seg*256+256). Phases of 64 steps:
// P 0..1 warmup (no output; seg 0 reads clamped addrs then resets to true
// init), P 2..5 emit. All LDS traffic for a stream is wave-local -> no
// barriers; per-wave DS ordering + lgkm waits suffice.
//
// R7 pipeline per phase: {ds_write pf (prev prefetch) -> issue prefetch P+1 ->
// sched_barrier -> lgkm wait -> compute -> [lgkm wait -> drain]}. The 16
// float4 prefetch regs stay live across compute, guaranteeing 16 KB in flight
// per wave while the VALU runs.
__global__ __launch_bounds__(64) void lif_seg_kernel(const float* __restrict__ x,
                                                     const float* __restrict__ beta_p,
                                                     const float* __restrict__ b,
                                                     const float* __restrict__ bn,
                                                     const float* __restrict__ ninv,
                                                     float* __restrict__ out) {
    __shared__ __align__(16) float lds[NSTR * SPITCH];   // 17408 B = 17 KB

    const int lane = threadIdx.x;        // = my stream index within block
    const int seg  = lane & 7;
    const int row  = blockIdx.x * 8 + (lane >> 3);
    const int c    = row & (C_DIM - 1);

    const float beta = beta_p[0];
    const float omb  = __fsub_rn(1.0f, beta);
    const float bnc  = bn[c];
    const float nic  = ninv[c];
    const float bc   = b[c];

    // Fill/drain lane mapping: instr q covers streams 4q..4q+3; lane i handles
    // stream 4q + (i>>4), float4 index i&15 (256 B per stream per instr).
    const int fh = lane >> 4;            // 0..3
    const int fj = lane & 15;            // 0..15

    float mem = 0.0f;
    int   mask = 0;

    float* my = &lds[lane * SPITCH];

    // ---- prologue: prefetch phase 0 into registers ----
    float4 pf[16];
    #pragma unroll
    for (int q = 0; q < 16; ++q) {
        const int s    = 4 * q + fh;
        const int srow = blockIdx.x * 8 + (s >> 3);
        int rel = (s & 7) * SEGL - WARM;                 // P = 0
        if (rel < 0) rel = 0;                            // clamped warmup reads (discarded)
        pf[q] = *(const float4*)(x + (size_t)srow * T_DIM + rel + 4 * fj);
    }

    #pragma unroll 1
    for (int P = 0; P < NPH; ++P) {
        // ---- commit prefetched phase P into padded LDS layout ----
        // (vmcnt waits here are ~free: loads were issued one full phase ago.
        //  DS in-order per wave: these writes cannot bypass the previous
        //  phase's compute/drain ds_reads.)
        #pragma unroll
        for (int q = 0; q < 16; ++q) {
            const int s = 4 * q + fh;
            *(float4*)(&lds[s * SPITCH + 4 * fj]) = pf[q];
        }

        // ---- issue prefetch for phase P+1 (in flight during compute) ----
        if (P + 1 < NPH) {
            #pragma unroll
            for (int q = 0; q < 16; ++q) {
                const int s    = 4 * q + fh;
                const int srow = blockIdx.x * 8 + (s >> 3);
                int rel = (s & 7) * SEGL - WARM + (P + 1) * PW;  // <0 only seg 0, P+1<2
                if (rel < 0) rel = 0;
                pf[q] = *(const float4*)(x + (size_t)srow * T_DIM + rel + 4 * fj);
            }
        }
        __builtin_amdgcn_sched_barrier(0);               // pin prefetch issue point
        __builtin_amdgcn_s_waitcnt(WAITCNT_LGKM0);       // writes visible to cross-lane reads

        if (P < WARM_PH) {
            // ---- warmup phase: 64 steps, no output ----
            #pragma unroll
            for (int g = 0; g < PW / 4; ++g) {
                float4 v = *(const float4*)(my + 4 * g);
                STEP4_NOSTORE(v);
            }
            if (P == WARM_PH - 1) {
                // seg 0 has no predecessor: restore the true initial state.
                if (seg == 0) { mem = 0.0f; mask = 0; }
            }
        } else {
            // ---- emit phase: 64 steps, spikes written back in place ----
            #pragma unroll
            for (int g = 0; g < PW / 4; ++g) {
                float4 v = *(const float4*)(my + 4 * g);
                float4 o;
                STEP4_STORE(v, o);
                *(float4*)(my + 4 * g) = o;
            }
            __builtin_amdgcn_s_waitcnt(WAITCNT_LGKM0);   // spikes visible to drain lanes

            // ---- drain: 16 coalesced stores (exactly tiles out, 1.00x) ----
            #pragma unroll
            for (int q = 0; q < 16; ++q) {
                const int s    = 4 * q + fh;
                const int srow = blockIdx.x * 8 + (s >> 3);
                const int rel  = (s & 7) * SEGL - WARM + P * PW;   // >= 0 for P >= 2
                float4 v = *(const float4*)(&lds[s * SPITCH + 4 * fj]);
                *(float4*)(out + (size_t)srow * T_DIM + rel + 4 * fj) = v;
            }
        }
    }
}

extern "C" void kernel_launch(void* const* d_in, const int* in_sizes, int n_in,
                              void* d_out, int out_size, void* d_ws, size_t ws_size,
                              hipStream_t stream) {
    const float* x    = (const float*)d_in[0];
    const float* w    = (const float*)d_in[1];
    const float* beta = (const float*)d_in[2];
    const float* b    = (const float*)d_in[3];
    float* out  = (float*)d_out;
    float* bn   = (float*)d_ws;          // 256 floats
    float* ninv = bn + C_DIM;            // 256 floats

    norm_kernel<<<C_DIM, 64, 0, stream>>>(w, b, bn, ninv);
    lif_seg_kernel<<<(NROWS * SEGS) / NSTR, NSTR, 0, stream>>>(x, beta, b, bn, ninv, out);
}

// Round 2
// 287.528 us; speedup vs baseline: 1.0427x; 1.0427x over previous
//
#include <hip/hip_runtime.h>

// x (B=64, C=256, T=2048) fp32; conv_weight (256,256,3); beta (1,); b (256,).
// Output spikes (B,C,T) fp32 in {0,1}.
//
// Established: R5 proved 128-step speculative warmup is bit-exact (absmax 0)
// and buys 8x occupancy. R2 proved the LDS-coalesced shell gives exactly 1.00x
// write amplification. R6 (92.6 us dispatch) was fill-BLOCKING: ~174 cyc per
// coalesced 1KB vmem instr = pure exposed latency (VALUBusy 12.7%).
// R7 pipelined the fill one phase ahead in pf[16] float4 -- but the register
// allocator kept VGPR_Count at 68 and SPILLED pf to scratch: WRITE_SIZE
// 131->327 MB, FETCH 97->172 MB, dispatch 135 us. The occupancy heuristic for
// a 64-thread block capped registers below what the pipeline needs.
// R8: identical structure + __launch_bounds__(64, 2). Grid = 2048 blocks =
// 8 waves/CU = 2 waves/SIMD; at min-2-waves/EU the cap is 256 VGPR/wave, so
// pf[16] (statically indexed, fully unrolled) stays in registers. 16 KB/wave
// in flight across the whole compute region, scratch traffic eliminated.
#define C_DIM 256
#define T_DIM 2048
#define B_DIM 64
#define NROWS (B_DIM * C_DIM)          // 16384
#define SEGS 8
#define SEGL (T_DIM / SEGS)            // 256 emitted timesteps per segment
#define WARM 128                       // speculative warmup steps (bit-exact, r5)
#define PW   64                        // phase window: floats per stream per phase
#define NPH  ((WARM + SEGL) / PW)      // 6 phases
#define WARM_PH (WARM / PW)            // 2 warmup phases
#define SPITCH 68                      // LDS floats per stream: 64 + 4 pad ->
                                       // bank-quad (17s+g)%8 = (s+g)%8: even 8-lane spread
#define NSTR 64                        // streams per block (= wave size)

__device__ __forceinline__ float sqrn(float v) { return __fmul_rn(v, v); }

// norm[c] = sum of squares of 768 floats in numpy's exact pairwise order
// (768->384->192->96; 96-blocks via 8-accumulator unrolled loop).
// Verified bit-exact (rounds 1-7 absmax 0). DO NOT change the summation tree.
__global__ __launch_bounds__(64) void norm_kernel(const float* __restrict__ w,
                                                  const float* __restrict__ b,
                                                  float* __restrict__ bn,
                                                  float* __restrict__ ninv) {
    const int c = blockIdx.x;
    const int k = threadIdx.x;
    __shared__ float q[8];
    if (k < 8) {
        const float* a = w + c * 768 + k * 96;
        float r0 = sqrn(a[0]), r1 = sqrn(a[1]), r2 = sqrn(a[2]), r3 = sqrn(a[3]);
        float r4 = sqrn(a[4]), r5 = sqrn(a[5]), r6 = sqrn(a[6]), r7 = sqrn(a[7]);
        #pragma unroll
        for (int i = 8; i < 96; i += 8) {
            r0 = __fadd_rn(r0, sqrn(a[i + 0]));
            r1 = __fadd_rn(r1, sqrn(a[i + 1]));
            r2 = __fadd_rn(r2, sqrn(a[i + 2]));
            r3 = __fadd_rn(r3, sqrn(a[i + 3]));
            r4 = __fadd_rn(r4, sqrn(a[i + 4]));
            r5 = __fadd_rn(r5, sqrn(a[i + 5]));
            r6 = __fadd_rn(r6, sqrn(a[i + 6]));
            r7 = __fadd_rn(r7, sqrn(a[i + 7]));
        }
        q[k] = __fadd_rn(__fadd_rn(__fadd_rn(r0, r1), __fadd_rn(r2, r3)),
                         __fadd_rn(__fadd_rn(r4, r5), __fadd_rn(r6, r7)));
    }
    __syncthreads();
    if (k == 0) {
        float s = __fadd_rn(__fadd_rn(__fadd_rn(q[0], q[1]), __fadd_rn(q[2], q[3])),
                            __fadd_rn(__fadd_rn(q[4], q[5]), __fadd_rn(q[6], q[7])));
        bn[c]   = __fmul_rn(b[c], s);
        ninv[c] = 1.0f / __fadd_rn(s, 1e-8f);
    }
}

// One LIF step, bit-exact vs numpy semantics (verified absmax 0, rounds 4-7):
// speculative dual-path update + sign-bit select, no VCC.
__device__ __forceinline__ float step_fast(float xw, float& mem, int& mask,
                                           float bnc, float beta, float nic, float bc) {
    float m0 = __fmul_rn(mem, beta);
    float m1 = __fmul_rn(__fsub_rn(mem, bnc), beta);
    m0 = __fadd_rn(m0, xw);
    m1 = __fadd_rn(m1, xw);
    int mi = (__float_as_int(m1) & mask) | (__float_as_int(m0) & ~mask);
    mem = __int_as_float(mi);
    float p = __fmul_rn(mem, nic);
    float d = __fsub_rn(bc, p);
    mask = __float_as_int(d) >> 31;                 // -1 if spike else 0
    return __int_as_float(mask & 0x3f800000);       // 1.0f or 0.0f
}

#define STEP4_NOSTORE(v)                                                   \
    do {                                                                   \
        float xw0 = __fmul_rn((v).x, omb);                                 \
        float xw1 = __fmul_rn((v).y, omb);                                 \
        float xw2 = __fmul_rn((v).z, omb);                                 \
        float xw3 = __fmul_rn((v).w, omb);                                 \
        (void)step_fast(xw0, mem, mask, bnc, beta, nic, bc);               \
        (void)step_fast(xw1, mem, mask, bnc, beta, nic, bc);               \
        (void)step_fast(xw2, mem, mask, bnc, beta, nic, bc);               \
        (void)step_fast(xw3, mem, mask, bnc, beta, nic, bc);               \
    } while (0)

#define STEP4_STORE(v, o)                                                  \
    do {                                                                   \
        float xw0 = __fmul_rn((v).x, omb);                                 \
        float xw1 = __fmul_rn((v).y, omb);                                 \
        float xw2 = __fmul_rn((v).z, omb);                                 \
        float xw3 = __fmul_rn((v).w, omb);                                 \
        (o).x = step_fast(xw0, mem, mask, bnc, beta, nic, bc);             \
        (o).y = step_fast(xw1, mem, mask, bnc, beta, nic, bc);             \
        (o).z = step_fast(xw2, mem, mask, bnc, beta, nic, bc);             \
        (o).w = step_fast(xw3, mem, mask, bnc, beta, nic, bc);             \
    } while (0)

// lgkm-only wait: cross-lane LDS handoff within a wave (proven in r2).
#define WAITCNT_LGKM0  0xC07F

// Block = 1 wave = 64 streams (8 rows x 8 segs). 2048 blocks = 8 waves/CU.
// Stream s: row = blockIdx.x*8 + (s>>3), seg = s&7, covers local steps
// [0,384) = global t in [seg*256-128, seg*256+256). Phases of 64 steps:
// P 0..1 warmup (no output; seg 0 reads clamped addrs then resets to true
// init), P 2..5 emit. All LDS traffic for a stream is wave-local -> no
// barriers; per-wave DS ordering + lgkm waits suffice.
//
// Pipeline per phase: {ds_write pf (prev prefetch) -> issue prefetch P+1 ->
// sched_barrier -> lgkm wait -> compute -> [lgkm wait -> drain]}. The 16
// float4 prefetch regs stay live across compute, guaranteeing 16 KB in flight
// per wave while the VALU runs. launch_bounds(64,2): 2 waves/EU min -> 256
// VGPR cap -> pf stays in registers (the R7 spill is the one thing fixed here).
__global__ __launch_bounds__(64, 2) void lif_seg_kernel(const float* __restrict__ x,
                                                        const float* __restrict__ beta_p,
                                                        const float* __restrict__ b,
                                                        const float* __restrict__ bn,
                                                        const float* __restrict__ ninv,
                                                        float* __restrict__ out) {
    __shared__ __align__(16) float lds[NSTR * SPITCH];   // 17408 B = 17 KB

    const int lane = threadIdx.x;        // = my stream index within block
    const int seg  = lane & 7;
    const int row  = blockIdx.x * 8 + (lane >> 3);
    const int c    = row & (C_DIM - 1);

    const float beta = beta_p[0];
    const float omb  = __fsub_rn(1.0f, beta);
    const float bnc  = bn[c];
    const float nic  = ninv[c];
    const float bc   = b[c];

    // Fill/drain lane mapping: instr q covers streams 4q..4q+3; lane i handles
    // stream 4q + (i>>4), float4 index i&15 (256 B per stream per instr).
    const int fh = lane >> 4;            // 0..3
    const int fj = lane & 15;            // 0..15

    float mem = 0.0f;
    int   mask = 0;

    float* my = &lds[lane * SPITCH];

    // ---- prologue: prefetch phase 0 into registers ----
    float4 pf[16];
    #pragma unroll
    for (int q = 0; q < 16; ++q) {
        const int s    = 4 * q + fh;
        const int srow = blockIdx.x * 8 + (s >> 3);
        int rel = (s & 7) * SEGL - WARM;                 // P = 0
        if (rel < 0) rel = 0;                            // clamped warmup reads (discarded)
        pf[q] = *(const float4*)(x + (size_t)srow * T_DIM + rel + 4 * fj);
    }

    #pragma unroll 1
    for (int P = 0; P < NPH; ++P) {
        // ---- commit prefetched phase P into padded LDS layout ----
        // (vmcnt waits here are ~free: loads were issued one full phase ago.
        //  DS in-order per wave: these writes cannot bypass the previous
        //  phase's compute/drain ds_reads.)
        #pragma unroll
        for (int q = 0; q < 16; ++q) {
            const int s = 4 * q + fh;
            *(float4*)(&lds[s * SPITCH + 4 * fj]) = pf[q];
        }

        // ---- issue prefetch for phase P+1 (in flight during compute) ----
        if (P + 1 < NPH) {
            #pragma unroll
            for (int q = 0; q < 16; ++q) {
                const int s    = 4 * q + fh;
                const int srow = blockIdx.x * 8 + (s >> 3);
                int rel = (s & 7) * SEGL - WARM + (P + 1) * PW;  // <0 only seg 0, P+1<2
                if (rel < 0) rel = 0;
                pf[q] = *(const float4*)(x + (size_t)srow * T_DIM + rel + 4 * fj);
            }
        }
        __builtin_amdgcn_sched_barrier(0);               // pin prefetch issue point
        __builtin_amdgcn_s_waitcnt(WAITCNT_LGKM0);       // writes visible to cross-lane reads

        if (P < WARM_PH) {
            // ---- warmup phase: 64 steps, no output ----
            #pragma unroll
            for (int g = 0; g < PW / 4; ++g) {
                float4 v = *(const float4*)(my + 4 * g);
                STEP4_NOSTORE(v);
            }
            if (P == WARM_PH - 1) {
                // seg 0 has no predecessor: restore the true initial state.
                if (seg == 0) { mem = 0.0f; mask = 0; }
            }
        } else {
            // ---- emit phase: 64 steps, spikes written back in place ----
            #pragma unroll
            for (int g = 0; g < PW / 4; ++g) {
                float4 v = *(const float4*)(my + 4 * g);
                float4 o;
                STEP4_STORE(v, o);
                *(float4*)(my + 4 * g) = o;
            }
            __builtin_amdgcn_s_waitcnt(WAITCNT_LGKM0);   // spikes visible to drain lanes

            // ---- drain: 16 coalesced stores (exactly tiles out, 1.00x) ----
            #pragma unroll
            for (int q = 0; q < 16; ++q) {
                const int s    = 4 * q + fh;
                const int srow = blockIdx.x * 8 + (s >> 3);
                const int rel  = (s & 7) * SEGL - WARM + P * PW;   // >= 0 for P >= 2
                float4 v = *(const float4*)(&lds[s * SPITCH + 4 * fj]);
                *(float4*)(out + (size_t)srow * T_DIM + rel + 4 * fj) = v;
            }
        }
    }
}

extern "C" void kernel_launch(void* const* d_in, const int* in_sizes, int n_in,
                              void* d_out, int out_size, void* d_ws, size_t ws_size,
                              hipStream_t stream) {
    const float* x    = (const float*)d_in[0];
    const float* w    = (const float*)d_in[1];
    const float* beta = (const float*)d_in[2];
    const float* b    = (const float*)d_in[3];
    float* out  = (float*)d_out;
    float* bn   = (float*)d_ws;          // 256 floats
    float* ninv = bn + C_DIM;            // 256 floats

    norm_kernel<<<C_DIM, 64, 0, stream>>>(w, b, bn, ninv);
    lif_seg_kernel<<<(NROWS * SEGS) / NSTR, NSTR, 0, stream>>>(x, beta, b, bn, ninv, out);
}

// Round 3
// 250.040 us; speedup vs baseline: 1.1990x; 1.1499x over previous
//
#include <hip/hip_runtime.h>

// x (B=64, C=256, T=2048) fp32; conv_weight (256,256,3); beta (1,); b (256,).
// Output spikes (B,C,T) fp32 in {0,1}.
//
// Established: R5 proved 128-step speculative warmup is bit-exact (absmax 0)
// and buys 8x occupancy. R2 proved the LDS-coalesced shell gives 1.00x write
// amplification. R6 (92.6 us dispatch) was fill-BLOCKING: ~174 cyc per 1KB
// vmem instr = pure exposed latency (VALUBusy 12.7%).
// R7/R8 tried pipelining the fill one phase ahead via pf[16] float4 -- FAILED
// identically (VGPR 68, WRITE 327 MB, 132 us): SROA runs BEFORE loop unroll,
// so pf[q] with loop-variable q never left its alloca -> scratch, +192 MB of
// spill writes per dispatch (6 phases x 2048 blk x 16 KB). launch_bounds was
// irrelevant: regalloc never saw the array.
// R9: same pipeline, but pf as 16 NAMED float4 scalars via X-macro (no array,
// no alloca, guaranteed SSA). launch_bounds(64,2) kept: grid = 2048 blocks =
// 2 waves/SIMD, so the ~150-VGPR live set is legal. 16 KB/wave in flight
// across the whole compute region.
#define C_DIM 256
#define T_DIM 2048
#define B_DIM 64
#define NROWS (B_DIM * C_DIM)          // 16384
#define SEGS 8
#define SEGL (T_DIM / SEGS)            // 256 emitted timesteps per segment
#define WARM 128                       // speculative warmup steps (bit-exact, r5)
#define PW   64                        // phase window: floats per stream per phase
#define NPH  ((WARM + SEGL) / PW)      // 6 phases
#define WARM_PH (WARM / PW)            // 2 warmup phases
#define SPITCH 68                      // LDS floats per stream: 64 + 4 pad ->
                                       // bank-quad (17s+g)%8 = (s+g)%8: even 8-lane spread
#define NSTR 64                        // streams per block (= wave size)

__device__ __forceinline__ float sqrn(float v) { return __fmul_rn(v, v); }

// norm[c] = sum of squares of 768 floats in numpy's exact pairwise order
// (768->384->192->96; 96-blocks via 8-accumulator unrolled loop).
// Verified bit-exact (rounds 1-8 absmax 0). DO NOT change the summation tree.
__global__ __launch_bounds__(64) void norm_kernel(const float* __restrict__ w,
                                                  const float* __restrict__ b,
                                                  float* __restrict__ bn,
                                                  float* __restrict__ ninv) {
    const int c = blockIdx.x;
    const int k = threadIdx.x;
    __shared__ float q[8];
    if (k < 8) {
        const float* a = w + c * 768 + k * 96;
        float r0 = sqrn(a[0]), r1 = sqrn(a[1]), r2 = sqrn(a[2]), r3 = sqrn(a[3]);
        float r4 = sqrn(a[4]), r5 = sqrn(a[5]), r6 = sqrn(a[6]), r7 = sqrn(a[7]);
        #pragma unroll
        for (int i = 8; i < 96; i += 8) {
            r0 = __fadd_rn(r0, sqrn(a[i + 0]));
            r1 = __fadd_rn(r1, sqrn(a[i + 1]));
            r2 = __fadd_rn(r2, sqrn(a[i + 2]));
            r3 = __fadd_rn(r3, sqrn(a[i + 3]));
            r4 = __fadd_rn(r4, sqrn(a[i + 4]));
            r5 = __fadd_rn(r5, sqrn(a[i + 5]));
            r6 = __fadd_rn(r6, sqrn(a[i + 6]));
            r7 = __fadd_rn(r7, sqrn(a[i + 7]));
        }
        q[k] = __fadd_rn(__fadd_rn(__fadd_rn(r0, r1), __fadd_rn(r2, r3)),
                         __fadd_rn(__fadd_rn(r4, r5), __fadd_rn(r6, r7)));
    }
    __syncthreads();
    if (k == 0) {
        float s = __fadd_rn(__fadd_rn(__fadd_rn(q[0], q[1]), __fadd_rn(q[2], q[3])),
                            __fadd_rn(__fadd_rn(q[4], q[5]), __fadd_rn(q[6], q[7])));
        bn[c]   = __fmul_rn(b[c], s);
        ninv[c] = 1.0f / __fadd_rn(s, 1e-8f);
    }
}

// One LIF step, bit-exact vs numpy semantics (verified absmax 0, rounds 4-8):
// speculative dual-path update + sign-bit select, no VCC.
__device__ __forceinline__ float step_fast(float xw, float& mem, int& mask,
                                           float bnc, float beta, float nic, float bc) {
    float m0 = __fmul_rn(mem, beta);
    float m1 = __fmul_rn(__fsub_rn(mem, bnc), beta);
    m0 = __fadd_rn(m0, xw);
    m1 = __fadd_rn(m1, xw);
    int mi = (__float_as_int(m1) & mask) | (__float_as_int(m0) & ~mask);
    mem = __int_as_float(mi);
    float p = __fmul_rn(mem, nic);
    float d = __fsub_rn(bc, p);
    mask = __float_as_int(d) >> 31;                 // -1 if spike else 0
    return __int_as_float(mask & 0x3f800000);       // 1.0f or 0.0f
}

#define STEP4_NOSTORE(v)                                                   \
    do {                                                                   \
        float xw0 = __fmul_rn((v).x, omb);                                 \
        float xw1 = __fmul_rn((v).y, omb);                                 \
        float xw2 = __fmul_rn((v).z, omb);                                 \
        float xw3 = __fmul_rn((v).w, omb);                                 \
        (void)step_fast(xw0, mem, mask, bnc, beta, nic, bc);               \
        (void)step_fast(xw1, mem, mask, bnc, beta, nic, bc);               \
        (void)step_fast(xw2, mem, mask, bnc, beta, nic, bc);               \
        (void)step_fast(xw3, mem, mask, bnc, beta, nic, bc);               \
    } while (0)

#define STEP4_STORE(v, o)                                                  \
    do {                                                                   \
        float xw0 = __fmul_rn((v).x, omb);                                 \
        float xw1 = __fmul_rn((v).y, omb);                                 \
        float xw2 = __fmul_rn((v).z, omb);                                 \
        float xw3 = __fmul_rn((v).w, omb);                                 \
        (o).x = step_fast(xw0, mem, mask, bnc, beta, nic, bc);             \
        (o).y = step_fast(xw1, mem, mask, bnc, beta, nic, bc);             \
        (o).z = step_fast(xw2, mem, mask, bnc, beta, nic, bc);             \
        (o).w = step_fast(xw3, mem, mask, bnc, beta, nic, bc);             \
    } while (0)

// lgkm-only wait: cross-lane LDS handoff within a wave (proven in r2).
#define WAITCNT_LGKM0  0xC07F

// X-macro over the 16 prefetch registers. Named scalars = guaranteed SSA
// (no alloca for SROA to miss). M(q, v) applied for q = 0..15.
#define PF_LIST(M) \
    M(0, pf0)  M(1, pf1)  M(2, pf2)  M(3, pf3)  \
    M(4, pf4)  M(5, pf5)  M(6, pf6)  M(7, pf7)  \
    M(8, pf8)  M(9, pf9)  M(10, pf10) M(11, pf11) \
    M(12, pf12) M(13, pf13) M(14, pf14) M(15, pf15)

// Block = 1 wave = 64 streams (8 rows x 8 segs). 2048 blocks = 8 waves/CU.
// Stream s: row = blockIdx.x*8 + (s>>3), seg = s&7, covers local steps
// [0,384) = global t in [seg*256-128, seg*256+256). Phases of 64 steps:
// P 0..1 warmup (no output; seg 0 reads clamped addrs then resets to true
// init), P 2..5 emit. All LDS traffic for a stream is wave-local -> no
// barriers; per-wave DS ordering + lgkm waits suffice.
//
// Pipeline per phase: {ds_write pf (prev prefetch) -> issue prefetch P+1 ->
// sched_barrier -> lgkm wait -> compute -> [lgkm wait -> drain]}. The 16
// float4 prefetch regs stay live across compute: 16 KB/wave in flight while
// the VALU runs.
__global__ __launch_bounds__(64, 2) void lif_seg_kernel(const float* __restrict__ x,
                                                        const float* __restrict__ beta_p,
                                                        const float* __restrict__ b,
                                                        const float* __restrict__ bn,
                                                        const float* __restrict__ ninv,
                                                        float* __restrict__ out) {
    __shared__ __align__(16) float lds[NSTR * SPITCH];   // 17408 B = 17 KB

    const int lane = threadIdx.x;        // = my stream index within block
    const int seg  = lane & 7;
    const int row  = blockIdx.x * 8 + (lane >> 3);
    const int c    = row & (C_DIM - 1);

    const float beta = beta_p[0];
    const float omb  = __fsub_rn(1.0f, beta);
    const float bnc  = bn[c];
    const float nic  = ninv[c];
    const float bc   = b[c];

    // Fill/drain lane mapping: instr q covers streams 4q..4q+3; lane i handles
    // stream 4q + (i>>4), float4 index i&15 (256 B per stream per instr).
    const int fh = lane >> 4;            // 0..3
    const int fj = lane & 15;            // 0..15

    float mem = 0.0f;
    int   mask = 0;

    float* my = &lds[lane * SPITCH];

    float4 pf0, pf1, pf2, pf3, pf4, pf5, pf6, pf7;
    float4 pf8, pf9, pf10, pf11, pf12, pf13, pf14, pf15;

    // ---- prologue: prefetch phase 0 into registers ----
#define PF_LOAD0(q, v)                                                        \
    {                                                                         \
        const int s_    = 4 * (q) + fh;                                       \
        const int srow_ = blockIdx.x * 8 + (s_ >> 3);                         \
        int rel_ = (s_ & 7) * SEGL - WARM;               /* P = 0 */          \
        if (rel_ < 0) rel_ = 0;        /* clamped warmup reads (discarded) */ \
        v = *(const float4*)(x + (size_t)srow_ * T_DIM + rel_ + 4 * fj);      \
    }
    PF_LIST(PF_LOAD0)
#undef PF_LOAD0

    #pragma unroll 1
    for (int P = 0; P < NPH; ++P) {
        // ---- commit prefetched phase P into padded LDS layout ----
        // (vmcnt wait here is ~free: loads were issued one full phase ago.
        //  DS in-order per wave: these writes cannot bypass the previous
        //  phase's compute/drain ds_reads.)
#define PF_COMMIT(q, v)                                                       \
        {                                                                     \
            const int s_ = 4 * (q) + fh;                                      \
            *(float4*)(&lds[s_ * SPITCH + 4 * fj]) = v;                       \
        }
        PF_LIST(PF_COMMIT)
#undef PF_COMMIT

        // ---- issue prefetch for phase P+1 (in flight during compute) ----
        if (P + 1 < NPH) {
#define PF_LOADN(q, v)                                                        \
            {                                                                 \
                const int s_    = 4 * (q) + fh;                               \
                const int srow_ = blockIdx.x * 8 + (s_ >> 3);                 \
                int rel_ = (s_ & 7) * SEGL - WARM + (P + 1) * PW;             \
                if (rel_ < 0) rel_ = 0;      /* <0 only seg 0, P+1 < 2 */     \
                v = *(const float4*)(x + (size_t)srow_ * T_DIM + rel_ + 4 * fj); \
            }
            PF_LIST(PF_LOADN)
#undef PF_LOADN
        }
        __builtin_amdgcn_sched_barrier(0);               // pin prefetch issue point
        __builtin_amdgcn_s_waitcnt(WAITCNT_LGKM0);       // writes visible to cross-lane reads

        if (P < WARM_PH) {
            // ---- warmup phase: 64 steps, no output ----
            #pragma unroll
            for (int g = 0; g < PW / 4; ++g) {
                float4 v = *(const float4*)(my + 4 * g);
                STEP4_NOSTORE(v);
            }
            if (P == WARM_PH - 1) {
                // seg 0 has no predecessor: restore the true initial state.
                if (seg == 0) { mem = 0.0f; mask = 0; }
            }
        } else {
            // ---- emit phase: 64 steps, spikes written back in place ----
            #pragma unroll
            for (int g = 0; g < PW / 4; ++g) {
                float4 v = *(const float4*)(my + 4 * g);
                float4 o;
                STEP4_STORE(v, o);
                *(float4*)(my + 4 * g) = o;
            }
            __builtin_amdgcn_s_waitcnt(WAITCNT_LGKM0);   // spikes visible to drain lanes

            // ---- drain: 16 coalesced stores (exactly tiles out, 1.00x) ----
            #pragma unroll
            for (int q = 0; q < 16; ++q) {
                const int s    = 4 * q + fh;
                const int srow = blockIdx.x * 8 + (s >> 3);
                const int rel  = (s & 7) * SEGL - WARM + P * PW;   // >= 0 for P >= 2
                float4 v = *(const float4*)(&lds[s * SPITCH + 4 * fj]);
                *(float4*)(out + (size_t)srow * T_DIM + rel + 4 * fj) = v;
            }
        }
    }
}

extern "C" void kernel_launch(void* const* d_in, const int* in_sizes, int n_in,
                              void* d_out, int out_size, void* d_ws, size_t ws_size,
                              hipStream_t stream) {
    const float* x    = (const float*)d_in[0];
    const float* w    = (const float*)d_in[1];
    const float* beta = (const float*)d_in[2];
    const float* b    = (const float*)d_in[3];
    float* out  = (float*)d_out;
    float* bn   = (float*)d_ws;          // 256 floats
    float* ninv = bn + C_DIM;            // 256 floats

    norm_kernel<<<C_DIM, 64, 0, stream>>>(w, b, bn, ninv);
    lif_seg_kernel<<<(NROWS * SEGS) / NSTR, NSTR, 0, stream>>>(x, beta, b, bn, ninv, out);
}